// Round 5
// baseline (5388.705 us; speedup 1.0000x reference)
//
#include <hip/hip_runtime.h>

#define Bn 256
#define Tn 2048
#define Dn 40
#define Hn 128
#define Cn 35

typedef _Float16 h2 __attribute__((ext_vector_type(2)));
typedef int int4v __attribute__((ext_vector_type(4)));

__device__ __forceinline__ int imin(int a, int b) { return a < b ? a : b; }

__device__ __forceinline__ int sdot4(int a, int b, int c) {
#if __has_builtin(__builtin_amdgcn_sdot4)
  return __builtin_amdgcn_sdot4(a, b, c, false);
#else
  int r = c;
#pragma unroll
  for (int i = 0; i < 4; ++i)
    r += ((int)(a << (24 - 8 * i)) >> 24) * ((int)(b << (24 - 8 * i)) >> 24);
  return r;
#endif
}

__device__ __forceinline__ float fdot2f(h2 a, h2 b, float c) {
#if __has_builtin(__builtin_amdgcn_fdot2)
  return __builtin_amdgcn_fdot2(a, b, c, false);
#else
  return c + (float)(a[0]) * (float)(b[0]) + (float)(a[1]) * (float)(b[1]);
#endif
}

__device__ __forceinline__ h2 bch(int u) { return __builtin_bit_cast(h2, u); }

__device__ __forceinline__ int pk2i(float a, float b) {  // two f16 in one word
  h2 r; r[0] = (_Float16)a; r[1] = (_Float16)b;
  return __builtin_bit_cast(int, r);
}

__device__ __forceinline__ float rcpf_(float x) {
#if __has_builtin(__builtin_amdgcn_rcpf)
  return __builtin_amdgcn_rcpf(x);
#else
  return 1.f / x;
#endif
}

__device__ __forceinline__ float sigm(float v) {
  v = fmaxf(fminf(v, 60.f), -60.f);
  return rcpf_(1.f + __expf(-v));
}

__device__ __forceinline__ float tanha(float v) {
  v = fmaxf(fminf(v, 15.f), -15.f);
  const float e = __expf(2.f * v);
  return (e - 1.f) * rcpf_(e + 1.f);
}

__device__ __forceinline__ int q8c(float v) {  // round+clamp to [-127,127]
  v = fminf(fmaxf(v, -127.f), 127.f);
  return (int)__builtin_rintf(v);
}

__device__ __forceinline__ int pk4(int a, int b, int c, int d) {
  return (a & 255) | ((b & 255) << 8) | ((c & 255) << 16) | (d << 24);
}

// DPP quad-perm xor-1 / xor-2 (full-rate VALU cross-lane within quads)
__device__ __forceinline__ int dpp_x1(int v) {
  return __builtin_amdgcn_update_dpp(0, v, 0xB1, 0xF, 0xF, true);
}
__device__ __forceinline__ int dpp_x2(int v) {
  return __builtin_amdgcn_update_dpp(0, v, 0x4E, 0xF, 0xF, true);
}

#if __has_builtin(__builtin_amdgcn_global_load_lds)
#define HAVE_GLDS 1
__device__ __forceinline__ void gl_lds16(const float* g, float* l) {
  __builtin_amdgcn_global_load_lds(
      (const __attribute__((address_space(1))) unsigned int*)(const void*)g,
      (__attribute__((address_space(3))) unsigned int*)(void*)l, 16, 0, 0);
}
#endif

// quantize 128 f32 weights -> 32 packed-i8 words + scale (rowmax/127)
__device__ __forceinline__ void quantW128(const float* __restrict__ p,
                                          int* __restrict__ q, float& sc) {
  float m = 1e-30f;
#pragma unroll
  for (int i = 0; i < 32; ++i) {
    const float4 v = reinterpret_cast<const float4*>(p)[i];
    m = fmaxf(m, fmaxf(fmaxf(fabsf(v.x), fabsf(v.y)),
                       fmaxf(fabsf(v.z), fabsf(v.w))));
  }
  const float inv = 127.f / m;
  sc = m * (1.f / 127.f);
#pragma unroll
  for (int i = 0; i < 32; ++i) {
    const float4 v = reinterpret_cast<const float4*>(p)[i];
    q[i] = pk4(q8c(v.x * inv), q8c(v.y * inv), q8c(v.z * inv), q8c(v.w * inv));
  }
}

// readlane word w (0..319) from 5-reg stash (lane L holds flat[L+64k])
#define RLST(w) __builtin_amdgcn_readlane(                                  \
    ((w) < 64 ? st0 : (w) < 128 ? st1 : (w) < 192 ? st2 : (w) < 256 ? st3  \
                                                        : st4), (w) & 63)

#define MEMBAR() asm volatile("" ::: "memory")

// r11 = r10 with the launch-bounds bug fixed. r10's VGPR_Count=128 +
// WRITE_SIZE 32MB (scratch stores) + FETCH 59MB (scratch re-reads every
// step) prove __launch_bounds__(512, 2) capped waves at 128 VGPRs: the
// second arg acted as min-BLOCKS-per-CU (CUDA semantics) -> 2 blocks x 8
// waves = 4 waves/SIMD -> 512/4 = 128 regs, and all four 32-int weight
// arrays spilled. The r10 split itself is correct: 128 weight ints + ~60
// working regs ~= 190 < 256 VALU-addressable. (512,1): under either
// semantics the cap is >=256. Everything else identical to r10:
//   w0/w1 L0a/L0b   w2/w3 L1a/L1b   w4/w5 TERMa/b   w6/w7 XPa/b
// zero-hop recurrences (h in-register via DPP quad pack, partner half via
// one broadcast LDS word), feed-forward edges on >=3-slack rings, flag
// protocol: publish = lgkmcnt(0) + ds_write, monotone counters, cached
// polls (proven in r9/r10 -- absmax bit-identical across rounds).
__global__ __launch_bounds__(512, 1) void lstm2_fused(
    const float* __restrict__ x,
    const int*   __restrict__ length,
    const float* __restrict__ Wih0, const float* __restrict__ Whh0,
    const float* __restrict__ bih0, const float* __restrict__ bhh0,
    const float* __restrict__ Wih1, const float* __restrict__ Whh1,
    const float* __restrict__ bih1, const float* __restrict__ bhh1,
    const float* __restrict__ gam,  const float* __restrict__ bet,
    const float* __restrict__ fcw,  const float* __restrict__ fcb,
    float* __restrict__ out)
{
  __shared__ __align__(16) float s_xraw[160 * 4];  // 2.5 KiB raw x chunk
  __shared__ int   s_xh2[320];                     // 1.25 KiB f16 x chunk
  __shared__ float s_xp[2][16][8][64];             // 64 KiB x-projection
  __shared__ float s_term[4][4][2][64];            // 8 KiB ih-term ring
  __shared__ int   s_h0q[4][32];                   // 4-deep packed i8 h0 ring
  __shared__ int   s_h1q[4][32];                   // 4-deep packed i8 h1 ring
  __shared__ __align__(32) int s_flag[8];          // L0a,L0b,L1a,L1b,Ta,Tb,Xa,Xb
  __shared__ float s_h1f[128];
  __shared__ float s_hn[128];

  const int tid  = threadIdx.x;
  const int lane = tid & 63;
  const int wv   = tid >> 6;          // wave 0..7
  const int b    = blockIdx.x;
  const int len  = length[b];         // 1..2048

  // ---- chunk-0 raw prefetch (XP waves; hidden under zero-init) ----
  if (wv == 6) {
    const float* xs = x + (size_t)b * Tn * Dn;
#if HAVE_GLDS
    gl_lds16(xs + lane * 4,        &s_xraw[0]);
    gl_lds16(xs + (lane + 64) * 4, &s_xraw[256]);
#else
    *(float4*)&s_xraw[lane * 4] = *(const float4*)(xs + lane * 4);
    *(float4*)&s_xraw[(lane + 64) * 4] = *(const float4*)(xs + (lane + 64) * 4);
#endif
  } else if (wv == 7 && lane < 32) {
    const float* xs = x + (size_t)b * Tn * Dn;
#if HAVE_GLDS
    gl_lds16(xs + (lane + 128) * 4, &s_xraw[512]);
#else
    *(float4*)&s_xraw[(lane + 128) * 4] = *(const float4*)(xs + (lane + 128) * 4);
#endif
  }
  if (tid < 128) { ((int*)s_h0q)[tid] = 0; ((int*)s_h1q)[tid] = 0; }
  if (tid < 8) s_flag[tid] = 0;
  __syncthreads();                 // glds drained; zeros visible
  if (tid < 160) {                 // convert chunk 0 to f16 stash
    const float4 v = *(const float4*)&s_xraw[4 * tid];
    s_xh2[2 * tid]     = pk2i(v.x, v.y);
    s_xh2[2 * tid + 1] = pk2i(v.z, v.w);
  }
  __syncthreads();                 // stash ready for both XP halves

  const __attribute__((address_space(3))) int* flagp3 =
      (const __attribute__((address_space(3))) int*)(const void*)s_flag;
  int4v f03 = {0, 0, 0, 0}, f47 = {0, 0, 0, 0};

#define READFLAGS()                                                          \
  asm volatile("ds_read_b128 %0, %2\n\tds_read_b128 %1, %2 offset:16\n\t"    \
               "s_waitcnt lgkmcnt(0)"                                        \
               : "=v"(f03), "=v"(f47) : "v"(flagp3) : "memory")
#define PUBLISH(idx, val)                                                    \
  do {                                                                       \
    MEMBAR();                                                                \
    asm volatile("s_waitcnt lgkmcnt(0)" ::: "memory");                       \
    *(volatile int*)&s_flag[idx] = (val);                                    \
  } while (0)
#define POLL(COND)                                                           \
  do {                                                                       \
    if (!(COND)) {                                                           \
      for (;;) {                                                             \
        READFLAGS();                                                         \
        if (COND) break;                                                     \
        __builtin_amdgcn_s_sleep(1);                                         \
      }                                                                      \
    }                                                                        \
    MEMBAR();                                                                \
  } while (0)

  if (wv < 2) {
    // ================= L0 half (units 64*half .. 64*half+63) =============
    const int half = wv;
    const int u = (half << 6) | lane;
    int qI[32], qF[32], qG[32], qO[32];
    float sI, sF, sG, sO;
    quantW128(Whh0 + (size_t)u * Hn, qI, sI);
    quantW128(Whh0 + (size_t)(u + 128) * Hn, qF, sF);
    quantW128(Whh0 + (size_t)(u + 256) * Hn, qG, sG);
    quantW128(Whh0 + (size_t)(u + 384) * Hn, qO, sO);
    sI *= (1.f / 127.f); sF *= (1.f / 127.f);
    sG *= (1.f / 127.f); sO *= (1.f / 127.f);
    const float bI = bih0[u]       + bhh0[u];
    const float bF = bih0[u + 128] + bhh0[u + 128];
    const float bG = bih0[u + 256] + bhh0[u + 256];
    const float bO = bih0[u + 384] + bhh0[u + 384];
    const int jo = half << 4, jp = (half ^ 1) << 4;
    float c0 = 0.f;
    int wA = 0;  // own 16 packed words (word jo+q at quad q lanes)
#pragma unroll 1
    for (int t = 0; t < len; ++t) {
      const int tl = t & 15;
      POLL(f03[half ^ 1] >= t && imin(f47[0], f47[1]) >= t - 3 &&
           (tl != 0 || imin(f47[2], f47[3]) >= 2 * (t >> 4) + 1));
      // partner h0 half (words jp..jp+15), broadcast read
      const int pw = s_h0q[(t + 3) & 3][jp + (lane & 15)];
      const int cs = (t >> 4) & 1;
      const float xI = s_xp[cs][tl][half][lane];
      const float xF = s_xp[cs][tl][half + 2][lane];
      const float xG = s_xp[cs][tl][half + 4][lane];
      const float xO = s_xp[cs][tl][half + 6][lane];
      int aI = 0, aF = 0, aG = 0, aO = 0;
      {
        int sw[16];
#pragma unroll
        for (int j = 0; j < 16; ++j) sw[j] = __builtin_amdgcn_readlane(wA, 4 * j);
#pragma unroll
        for (int j = 0; j < 16; ++j) {
          aI = sdot4(sw[j], qI[jo + j], aI); aF = sdot4(sw[j], qF[jo + j], aF);
          aG = sdot4(sw[j], qG[jo + j], aG); aO = sdot4(sw[j], qO[jo + j], aO);
        }
#pragma unroll
        for (int j = 0; j < 16; ++j) sw[j] = __builtin_amdgcn_readlane(pw, j);
#pragma unroll
        for (int j = 0; j < 16; ++j) {
          aI = sdot4(sw[j], qI[jp + j], aI); aF = sdot4(sw[j], qF[jp + j], aF);
          aG = sdot4(sw[j], qG[jp + j], aG); aO = sdot4(sw[j], qO[jp + j], aO);
        }
      }
      const float gi = bI + xI + (float)aI * sI;
      const float gf = bF + xF + (float)aF * sF;
      const float gg = bG + xG + (float)aG * sG;
      const float go = bO + xO + (float)aO * sO;
      c0 = sigm(gf) * c0 + sigm(gi) * tanha(gg);
      const float h = sigm(go) * tanha(c0);
      int v = (((int)__builtin_rintf(h * 127.f)) & 255) << (8 * (lane & 3));
      v |= dpp_x1(v); v |= dpp_x2(v);
      wA = v;
      if ((lane & 3) == 0) s_h0q[t & 3][jo + (lane >> 2)] = v;
      PUBLISH(wv, t + 1);
      READFLAGS();
    }
  } else if (wv < 4) {
    // ================= L1 half =================
    const int half = wv - 2;
    const int u = (half << 6) | lane;
    int qI[32], qF[32], qG[32], qO[32];
    float sI, sF, sG, sO;
    quantW128(Whh1 + (size_t)u * Hn, qI, sI);
    quantW128(Whh1 + (size_t)(u + 128) * Hn, qF, sF);
    quantW128(Whh1 + (size_t)(u + 256) * Hn, qG, sG);
    quantW128(Whh1 + (size_t)(u + 384) * Hn, qO, sO);
    sI *= (1.f / 127.f); sF *= (1.f / 127.f);
    sG *= (1.f / 127.f); sO *= (1.f / 127.f);
    const int jo = half << 4, jp = (half ^ 1) << 4;
    float c1 = 0.f;
    int wA = 0;
#pragma unroll 1
    for (int t = 0; t < len; ++t) {
      POLL(f03[2 + (half ^ 1)] >= t && imin(f47[0], f47[1]) >= t + 1);
      const int pw = s_h1q[(t + 3) & 3][jp + (lane & 15)];
      const float tvI = s_term[t & 3][0][half][lane];
      const float tvF = s_term[t & 3][1][half][lane];
      const float tvG = s_term[t & 3][2][half][lane];
      const float tvO = s_term[t & 3][3][half][lane];
      int aI = 0, aF = 0, aG = 0, aO = 0;
      {
        int sw[16];
#pragma unroll
        for (int j = 0; j < 16; ++j) sw[j] = __builtin_amdgcn_readlane(wA, 4 * j);
#pragma unroll
        for (int j = 0; j < 16; ++j) {
          aI = sdot4(sw[j], qI[jo + j], aI); aF = sdot4(sw[j], qF[jo + j], aF);
          aG = sdot4(sw[j], qG[jo + j], aG); aO = sdot4(sw[j], qO[jo + j], aO);
        }
#pragma unroll
        for (int j = 0; j < 16; ++j) sw[j] = __builtin_amdgcn_readlane(pw, j);
#pragma unroll
        for (int j = 0; j < 16; ++j) {
          aI = sdot4(sw[j], qI[jp + j], aI); aF = sdot4(sw[j], qF[jp + j], aF);
          aG = sdot4(sw[j], qG[jp + j], aG); aO = sdot4(sw[j], qO[jp + j], aO);
        }
      }
      const float gi = tvI + (float)aI * sI;
      const float gf = tvF + (float)aF * sF;
      const float gg = tvG + (float)aG * sG;
      const float go = tvO + (float)aO * sO;
      c1 = sigm(gf) * c1 + sigm(gi) * tanha(gg);
      const float h = sigm(go) * tanha(c1);
      if (t == len - 1) s_h1f[u] = h;
      int v = (((int)__builtin_rintf(h * 127.f)) & 255) << (8 * (lane & 3));
      v |= dpp_x1(v); v |= dpp_x2(v);
      wA = v;
      if ((lane & 3) == 0) s_h1q[t & 3][jo + (lane >> 2)] = v;
      PUBLISH(wv, t + 1);
      READFLAGS();
    }
  } else if (wv < 6) {
    // ================= TERM half: Wih1 . h0(t) for units of this half ====
    const int half = wv - 4;
    const int u = (half << 6) | lane;
    int qI[32], qF[32], qG[32], qO[32];
    float sI, sF, sG, sO;
    quantW128(Wih1 + (size_t)u * Hn, qI, sI);
    quantW128(Wih1 + (size_t)(u + 128) * Hn, qF, sF);
    quantW128(Wih1 + (size_t)(u + 256) * Hn, qG, sG);
    quantW128(Wih1 + (size_t)(u + 384) * Hn, qO, sO);
    sI *= (1.f / 127.f); sF *= (1.f / 127.f);
    sG *= (1.f / 127.f); sO *= (1.f / 127.f);
    const float bI = bih1[u]       + bhh1[u];
    const float bF = bih1[u + 128] + bhh1[u + 128];
    const float bG = bih1[u + 256] + bhh1[u + 256];
    const float bO = bih1[u + 384] + bhh1[u + 384];
#pragma unroll 1
    for (int t = 0; t < len; ++t) {
      POLL(f03[0] >= t + 1 && f03[1] >= t + 1 &&
           imin(f03[2], f03[3]) >= t - 3);
      const int vq = s_h0q[t & 3][lane & 31];  // full 32-word h0(t)
      int aI = 0, aF = 0, aG = 0, aO = 0;
      {
        int sw[32];
#pragma unroll
        for (int j = 0; j < 32; ++j) sw[j] = __builtin_amdgcn_readlane(vq, j);
#pragma unroll
        for (int j = 0; j < 32; ++j) {
          aI = sdot4(sw[j], qI[j], aI); aF = sdot4(sw[j], qF[j], aF);
          aG = sdot4(sw[j], qG[j], aG); aO = sdot4(sw[j], qO[j], aO);
        }
      }
      s_term[t & 3][0][half][lane] = bI + (float)aI * sI;
      s_term[t & 3][1][half][lane] = bF + (float)aF * sF;
      s_term[t & 3][2][half][lane] = bG + (float)aG * sG;
      s_term[t & 3][3][half][lane] = bO + (float)aO * sO;
      PUBLISH(wv, t + 1);
      READFLAGS();
    }
  } else {
    // ================= XP half: x -> f16 -> Wih0 rows of this half =======
    const int half = wv - 6;
    const int u = (half << 6) | lane;  // same rows as L0 half
    int wpA[20], wpB[20], wpC[20], wpD[20];
    {
      const float* p;
      p = Wih0 + (size_t)u * Dn;
#pragma unroll
      for (int w2 = 0; w2 < 20; ++w2) wpA[w2] = pk2i(p[2 * w2], p[2 * w2 + 1]);
      p = Wih0 + (size_t)(u + 128) * Dn;
#pragma unroll
      for (int w2 = 0; w2 < 20; ++w2) wpB[w2] = pk2i(p[2 * w2], p[2 * w2 + 1]);
      p = Wih0 + (size_t)(u + 256) * Dn;
#pragma unroll
      for (int w2 = 0; w2 < 20; ++w2) wpC[w2] = pk2i(p[2 * w2], p[2 * w2 + 1]);
      p = Wih0 + (size_t)(u + 384) * Dn;
#pragma unroll
      for (int w2 = 0; w2 < 20; ++w2) wpD[w2] = pk2i(p[2 * w2], p[2 * w2 + 1]);
    }
    const int nch = (len + 15) >> 4;
#pragma unroll 1
    for (int k = 0; k < nch; ++k) {
      const bool more = (k + 1 < nch);
      if (more) {  // prefetch raw chunk k+1 (own segments)
        const float* xs = x + ((size_t)b * Tn + (size_t)(k + 1) * 16) * Dn;
        if (half == 0) {
#if HAVE_GLDS
          gl_lds16(xs + lane * 4,        &s_xraw[0]);
          gl_lds16(xs + (lane + 64) * 4, &s_xraw[256]);
#else
          *(float4*)&s_xraw[lane * 4] = *(const float4*)(xs + lane * 4);
          *(float4*)&s_xraw[(lane + 64) * 4] = *(const float4*)(xs + (lane + 64) * 4);
#endif
        } else if (lane < 32) {
#if HAVE_GLDS
          gl_lds16(xs + (lane + 128) * 4, &s_xraw[512]);
#else
          *(float4*)&s_xraw[(lane + 128) * 4] = *(const float4*)(xs + (lane + 128) * 4);
#endif
        }
      }
      // project chunk k (partner must have converted chunk k: flag >= 2k)
      POLL(f47[2 + (half ^ 1)] >= 2 * k);
      {
        const int* flat = s_xh2;
        const int st0 = flat[lane], st1 = flat[lane + 64],
                  st2 = flat[lane + 128], st3 = flat[lane + 192],
                  st4 = flat[lane + 256];
#pragma unroll 1
        for (int tl = 0; tl < 16; ++tl) {
          float a0 = 0.f, a1 = 0.f, a2 = 0.f, a3 = 0.f;
#pragma unroll
          for (int w2 = 0; w2 < 20; ++w2) {
            const h2 s = bch(RLST(20 * tl + w2));
            a0 = fdot2f(s, bch(wpA[w2]), a0);
            a1 = fdot2f(s, bch(wpB[w2]), a1);
            a2 = fdot2f(s, bch(wpC[w2]), a2);
            a3 = fdot2f(s, bch(wpD[w2]), a3);
          }
          s_xp[k & 1][tl][half][lane]     = a0;
          s_xp[k & 1][tl][half + 2][lane] = a1;
          s_xp[k & 1][tl][half + 4][lane] = a2;
          s_xp[k & 1][tl][half + 6][lane] = a3;
        }
      }
      PUBLISH(wv, 2 * k + 1);
      if (more) {
        // convert chunk k+1 into shared stash: needs L0 past the buffer we
        // overwrite next AND partner done projecting chunk k from s_xh2
        POLL(imin(f03[0], f03[1]) >= 16 * k &&
             f47[2 + (half ^ 1)] >= 2 * k + 1);
#if HAVE_GLDS
        asm volatile("s_waitcnt vmcnt(0)" ::: "memory");
#endif
        if (half == 0) {
          float4 v = *(const float4*)&s_xraw[4 * lane];
          s_xh2[2 * lane] = pk2i(v.x, v.y);
          s_xh2[2 * lane + 1] = pk2i(v.z, v.w);
          v = *(const float4*)&s_xraw[4 * (lane + 64)];
          s_xh2[2 * (lane + 64)] = pk2i(v.x, v.y);
          s_xh2[2 * (lane + 64) + 1] = pk2i(v.z, v.w);
        } else if (lane < 32) {
          float4 v = *(const float4*)&s_xraw[4 * (lane + 128)];
          s_xh2[2 * (lane + 128)] = pk2i(v.x, v.y);
          s_xh2[2 * (lane + 128) + 1] = pk2i(v.z, v.w);
        }
      }
      PUBLISH(wv, 2 * k + 2);
      READFLAGS();
    }
  }

  __syncthreads();  // all chains done; s_h1f complete

  // ---- LayerNorm over H on wave 0 ----
  if (tid < 64) {
    const float a = s_h1f[tid], d = s_h1f[64 + tid];
    float s = a + d, q = a * a + d * d;
#pragma unroll
    for (int m = 32; m >= 1; m >>= 1) {
      s += __shfl_xor(s, m, 64);
      q += __shfl_xor(q, m, 64);
    }
    const float mu = s * (1.f / 128.f);
    float var = q * (1.f / 128.f) - mu * mu;
    var = fmaxf(var, 0.f);
    const float rstd = rsqrtf(var + 1e-5f);
    s_hn[tid]      = (a - mu) * rstd * gam[tid]      + bet[tid];
    s_hn[64 + tid] = (d - mu) * rstd * gam[64 + tid] + bet[64 + tid];
  }
  __syncthreads();

  // ---- FC head ----
  if (tid < Cn) {
    float acc = fcb[tid];
    const float* wp = fcw + tid * Hn;
#pragma unroll 4
    for (int k = 0; k < Hn; ++k) acc += s_hn[k] * wp[k];
    out[(size_t)b * Cn + tid] = acc;
  }
}

extern "C" void kernel_launch(void* const* d_in, const int* in_sizes, int n_in,
                              void* d_out, int out_size, void* d_ws, size_t ws_size,
                              hipStream_t stream) {
  (void)in_sizes; (void)n_in; (void)d_ws; (void)ws_size; (void)out_size;
  lstm2_fused<<<dim3(Bn), dim3(512), 0, stream>>>(
      (const float*)d_in[0],  (const int*)d_in[1],
      (const float*)d_in[2],  (const float*)d_in[3],
      (const float*)d_in[4],  (const float*)d_in[5],
      (const float*)d_in[6],  (const float*)d_in[7],
      (const float*)d_in[8],  (const float*)d_in[9],
      (const float*)d_in[10], (const float*)d_in[11],
      (const float*)d_in[12], (const float*)d_in[13],
      (float*)d_out);
}

// Round 7
// 2757.104 us; speedup vs baseline: 1.9545x; 1.9545x over previous
//
#include <hip/hip_runtime.h>

#define Bn 256
#define Tn 2048
#define Dn 40
#define Hn 128
#define Cn 35

typedef _Float16 h2 __attribute__((ext_vector_type(2)));
typedef int int4v __attribute__((ext_vector_type(4)));

__device__ __forceinline__ int imin(int a, int b) { return a < b ? a : b; }

__device__ __forceinline__ int sdot4(int a, int b, int c) {
#if __has_builtin(__builtin_amdgcn_sdot4)
  return __builtin_amdgcn_sdot4(a, b, c, false);
#else
  int r = c;
#pragma unroll
  for (int i = 0; i < 4; ++i)
    r += ((int)(a << (24 - 8 * i)) >> 24) * ((int)(b << (24 - 8 * i)) >> 24);
  return r;
#endif
}

__device__ __forceinline__ float fdot2f(h2 a, h2 b, float c) {
#if __has_builtin(__builtin_amdgcn_fdot2)
  return __builtin_amdgcn_fdot2(a, b, c, false);
#else
  return c + (float)(a[0]) * (float)(b[0]) + (float)(a[1]) * (float)(b[1]);
#endif
}

__device__ __forceinline__ h2 bch(int u) { return __builtin_bit_cast(h2, u); }

__device__ __forceinline__ int pk2i(float a, float b) {  // two f16 in one word
  h2 r; r[0] = (_Float16)a; r[1] = (_Float16)b;
  return __builtin_bit_cast(int, r);
}

__device__ __forceinline__ float rcpf_(float x) {
#if __has_builtin(__builtin_amdgcn_rcpf)
  return __builtin_amdgcn_rcpf(x);
#else
  return 1.f / x;
#endif
}

__device__ __forceinline__ float sigm(float v) {
  v = fmaxf(fminf(v, 60.f), -60.f);
  return rcpf_(1.f + __expf(-v));
}

__device__ __forceinline__ float tanha(float v) {
  v = fmaxf(fminf(v, 15.f), -15.f);
  const float e = __expf(2.f * v);
  return (e - 1.f) * rcpf_(e + 1.f);
}

__device__ __forceinline__ int q8c(float v) {  // round+clamp to [-127,127]
  v = fminf(fmaxf(v, -127.f), 127.f);
  return (int)__builtin_rintf(v);
}

__device__ __forceinline__ int pk4(int a, int b, int c, int d) {
  return (a & 255) | ((b & 255) << 8) | ((c & 255) << 16) | (d << 24);
}

// DPP quad-perm xor-1 / xor-2 (full-rate VALU cross-lane within quads)
__device__ __forceinline__ int dpp_x1(int v) {
  return __builtin_amdgcn_update_dpp(0, v, 0xB1, 0xF, 0xF, true);
}
__device__ __forceinline__ int dpp_x2(int v) {
  return __builtin_amdgcn_update_dpp(0, v, 0x4E, 0xF, 0xF, true);
}

#if __has_builtin(__builtin_amdgcn_global_load_lds)
#define HAVE_GLDS 1
__device__ __forceinline__ void gl_lds16(const float* g, float* l) {
  __builtin_amdgcn_global_load_lds(
      (const __attribute__((address_space(1))) unsigned int*)(const void*)g,
      (__attribute__((address_space(3))) unsigned int*)(void*)l, 16, 0, 0);
}
#endif

// streaming |max| over a 128-f32 row (same reduction order as r9's quantW128)
__device__ __forceinline__ float rowmax128(const float* __restrict__ p) {
  float m = 1e-30f;
#pragma unroll
  for (int i = 0; i < 32; ++i) {
    const float4 v = reinterpret_cast<const float4*>(p)[i];
    m = fmaxf(m, fmaxf(fmaxf(fabsf(v.x), fabsf(v.y)),
                       fmaxf(fabsf(v.z), fabsf(v.w))));
  }
  return m;
}

// quantize 16 packed words from word-offset `off` (RUNTIME offset applied to
// the GLOBAL pointer; destination indices are COMPILE-TIME -> stays in VGPRs.
// This is the r10/r11 scratch-spill fix: q[jo+j] with runtime jo forced the
// whole array to scratch -- rule #20.)
__device__ __forceinline__ void quant16(const float* __restrict__ p, int off,
                                        float inv, int* __restrict__ q) {
#pragma unroll
  for (int i = 0; i < 16; ++i) {
    const float4 v = reinterpret_cast<const float4*>(p)[off + i];
    q[i] = pk4(q8c(v.x * inv), q8c(v.y * inv), q8c(v.z * inv), q8c(v.w * inv));
  }
}

// quantize 128 f32 weights -> 32 packed-i8 words + scale (rowmax/127)
__device__ __forceinline__ void quantW128(const float* __restrict__ p,
                                          int* __restrict__ q, float& sc) {
  float m = 1e-30f;
#pragma unroll
  for (int i = 0; i < 32; ++i) {
    const float4 v = reinterpret_cast<const float4*>(p)[i];
    m = fmaxf(m, fmaxf(fmaxf(fabsf(v.x), fabsf(v.y)),
                       fmaxf(fabsf(v.z), fabsf(v.w))));
  }
  const float inv = 127.f / m;
  sc = m * (1.f / 127.f);
#pragma unroll
  for (int i = 0; i < 32; ++i) {
    const float4 v = reinterpret_cast<const float4*>(p)[i];
    q[i] = pk4(q8c(v.x * inv), q8c(v.y * inv), q8c(v.z * inv), q8c(v.w * inv));
  }
}

// readlane word w (0..319) from 5-reg stash (lane L holds flat[L+64k])
#define RLST(w) __builtin_amdgcn_readlane(                                  \
    ((w) < 64 ? st0 : (w) < 128 ? st1 : (w) < 192 ? st2 : (w) < 256 ? st3  \
                                                        : st4), (w) & 63)

#define MEMBAR() asm volatile("" ::: "memory")

// r13 = r12 resubmitted verbatim (r12's bench died to container-level infra
// failure -- no kernel output, no counters; sync protocol is byte-identical
// to r11 which completed fine, so no new hang path exists).
// r12 rationale: r10/r11 kept VGPR_Count=128 + 32MB WRITE_SIZE under BOTH
// launch_bounds settings => not a budget issue. Root cause (rule #20):
// qI[jo + j] with jo = half<<4 (RUNTIME, wave-id derived) -> runtime-indexed
// local array -> compiler places the whole 4x32-word weight set in SCRATCH;
// every step re-reads 512B/lane. Fix: split each weight array into
// own/partner 16-word halves (qIo/qIp/...) filled by quant16(), which
// applies the runtime offset to the GLOBAL pointer and writes with
// compile-time indices -> pure VGPRs (~190/wave, fits the 256 cap of
// 2 waves/SIMD). Quantization arithmetic is in the identical order as
// before -> absmax must stay bit-identical (0.03027344).
// Everything else unchanged from r11 (proven protocol):
//   w0/w1 L0a/L0b   w2/w3 L1a/L1b   w4/w5 TERMa/b   w6/w7 XPa/b
// zero-hop recurrences (h in-register via DPP quad pack, partner half via
// one broadcast LDS word), feed-forward edges on >=3-slack rings, flags:
// publish = lgkmcnt(0) + ds_write, monotone counters, cached polls.
__global__ __launch_bounds__(512, 1) void lstm2_fused(
    const float* __restrict__ x,
    const int*   __restrict__ length,
    const float* __restrict__ Wih0, const float* __restrict__ Whh0,
    const float* __restrict__ bih0, const float* __restrict__ bhh0,
    const float* __restrict__ Wih1, const float* __restrict__ Whh1,
    const float* __restrict__ bih1, const float* __restrict__ bhh1,
    const float* __restrict__ gam,  const float* __restrict__ bet,
    const float* __restrict__ fcw,  const float* __restrict__ fcb,
    float* __restrict__ out)
{
  __shared__ __align__(16) float s_xraw[160 * 4];  // 2.5 KiB raw x chunk
  __shared__ int   s_xh2[320];                     // 1.25 KiB f16 x chunk
  __shared__ float s_xp[2][16][8][64];             // 64 KiB x-projection
  __shared__ float s_term[4][4][2][64];            // 8 KiB ih-term ring
  __shared__ int   s_h0q[4][32];                   // 4-deep packed i8 h0 ring
  __shared__ int   s_h1q[4][32];                   // 4-deep packed i8 h1 ring
  __shared__ __align__(32) int s_flag[8];          // L0a,L0b,L1a,L1b,Ta,Tb,Xa,Xb
  __shared__ float s_h1f[128];
  __shared__ float s_hn[128];

  const int tid  = threadIdx.x;
  const int lane = tid & 63;
  const int wv   = tid >> 6;          // wave 0..7
  const int b    = blockIdx.x;
  const int len  = length[b];         // 1..2048

  // ---- chunk-0 raw prefetch (XP waves; hidden under zero-init) ----
  if (wv == 6) {
    const float* xs = x + (size_t)b * Tn * Dn;
#if HAVE_GLDS
    gl_lds16(xs + lane * 4,        &s_xraw[0]);
    gl_lds16(xs + (lane + 64) * 4, &s_xraw[256]);
#else
    *(float4*)&s_xraw[lane * 4] = *(const float4*)(xs + lane * 4);
    *(float4*)&s_xraw[(lane + 64) * 4] = *(const float4*)(xs + (lane + 64) * 4);
#endif
  } else if (wv == 7 && lane < 32) {
    const float* xs = x + (size_t)b * Tn * Dn;
#if HAVE_GLDS
    gl_lds16(xs + (lane + 128) * 4, &s_xraw[512]);
#else
    *(float4*)&s_xraw[(lane + 128) * 4] = *(const float4*)(xs + (lane + 128) * 4);
#endif
  }
  if (tid < 128) { ((int*)s_h0q)[tid] = 0; ((int*)s_h1q)[tid] = 0; }
  if (tid < 8) s_flag[tid] = 0;
  __syncthreads();                 // glds drained; zeros visible
  if (tid < 160) {                 // convert chunk 0 to f16 stash
    const float4 v = *(const float4*)&s_xraw[4 * tid];
    s_xh2[2 * tid]     = pk2i(v.x, v.y);
    s_xh2[2 * tid + 1] = pk2i(v.z, v.w);
  }
  __syncthreads();                 // stash ready for both XP halves

  const __attribute__((address_space(3))) int* flagp3 =
      (const __attribute__((address_space(3))) int*)(const void*)s_flag;
  int4v f03 = {0, 0, 0, 0}, f47 = {0, 0, 0, 0};

#define READFLAGS()                                                          \
  asm volatile("ds_read_b128 %0, %2\n\tds_read_b128 %1, %2 offset:16\n\t"    \
               "s_waitcnt lgkmcnt(0)"                                        \
               : "=v"(f03), "=v"(f47) : "v"(flagp3) : "memory")
#define PUBLISH(idx, val)                                                    \
  do {                                                                       \
    MEMBAR();                                                                \
    asm volatile("s_waitcnt lgkmcnt(0)" ::: "memory");                       \
    *(volatile int*)&s_flag[idx] = (val);                                    \
  } while (0)
#define POLL(COND)                                                           \
  do {                                                                       \
    if (!(COND)) {                                                           \
      for (;;) {                                                             \
        READFLAGS();                                                         \
        if (COND) break;                                                     \
        __builtin_amdgcn_s_sleep(1);                                         \
      }                                                                      \
    }                                                                        \
    MEMBAR();                                                                \
  } while (0)

  if (wv < 2) {
    // ================= L0 half (units 64*half .. 64*half+63) =============
    const int half = wv;
    const int u = (half << 6) | lane;
    const int jo = half << 4, jp = (half ^ 1) << 4;
    // own/partner-half weight words, compile-time indexed (VGPR-resident)
    int qIo[16], qIp[16], qFo[16], qFp[16];
    int qGo[16], qGp[16], qOo[16], qOp[16];
    float sI, sF, sG, sO;
    {
      const float* p;
      float m, inv;
      p = Whh0 + (size_t)u * Hn;
      m = rowmax128(p); inv = 127.f / m; sI = m * (1.f / 127.f);
      quant16(p, jo, inv, qIo); quant16(p, jp, inv, qIp);
      p = Whh0 + (size_t)(u + 128) * Hn;
      m = rowmax128(p); inv = 127.f / m; sF = m * (1.f / 127.f);
      quant16(p, jo, inv, qFo); quant16(p, jp, inv, qFp);
      p = Whh0 + (size_t)(u + 256) * Hn;
      m = rowmax128(p); inv = 127.f / m; sG = m * (1.f / 127.f);
      quant16(p, jo, inv, qGo); quant16(p, jp, inv, qGp);
      p = Whh0 + (size_t)(u + 384) * Hn;
      m = rowmax128(p); inv = 127.f / m; sO = m * (1.f / 127.f);
      quant16(p, jo, inv, qOo); quant16(p, jp, inv, qOp);
    }
    sI *= (1.f / 127.f); sF *= (1.f / 127.f);
    sG *= (1.f / 127.f); sO *= (1.f / 127.f);
    const float bI = bih0[u]       + bhh0[u];
    const float bF = bih0[u + 128] + bhh0[u + 128];
    const float bG = bih0[u + 256] + bhh0[u + 256];
    const float bO = bih0[u + 384] + bhh0[u + 384];
    float c0 = 0.f;
    int wA = 0;  // own 16 packed words (word jo+q at quad q lanes)
#pragma unroll 1
    for (int t = 0; t < len; ++t) {
      const int tl = t & 15;
      POLL(f03[half ^ 1] >= t && imin(f47[0], f47[1]) >= t - 3 &&
           (tl != 0 || imin(f47[2], f47[3]) >= 2 * (t >> 4) + 1));
      // partner h0 half (words jp..jp+15), broadcast read
      const int pw = s_h0q[(t + 3) & 3][jp + (lane & 15)];
      const int cs = (t >> 4) & 1;
      const float xI = s_xp[cs][tl][half][lane];
      const float xF = s_xp[cs][tl][half + 2][lane];
      const float xG = s_xp[cs][tl][half + 4][lane];
      const float xO = s_xp[cs][tl][half + 6][lane];
      int aI = 0, aF = 0, aG = 0, aO = 0;
      {
        int sw[16];
#pragma unroll
        for (int j = 0; j < 16; ++j) sw[j] = __builtin_amdgcn_readlane(wA, 4 * j);
#pragma unroll
        for (int j = 0; j < 16; ++j) {
          aI = sdot4(sw[j], qIo[j], aI); aF = sdot4(sw[j], qFo[j], aF);
          aG = sdot4(sw[j], qGo[j], aG); aO = sdot4(sw[j], qOo[j], aO);
        }
#pragma unroll
        for (int j = 0; j < 16; ++j) sw[j] = __builtin_amdgcn_readlane(pw, j);
#pragma unroll
        for (int j = 0; j < 16; ++j) {
          aI = sdot4(sw[j], qIp[j], aI); aF = sdot4(sw[j], qFp[j], aF);
          aG = sdot4(sw[j], qGp[j], aG); aO = sdot4(sw[j], qOp[j], aO);
        }
      }
      const float gi = bI + xI + (float)aI * sI;
      const float gf = bF + xF + (float)aF * sF;
      const float gg = bG + xG + (float)aG * sG;
      const float go = bO + xO + (float)aO * sO;
      c0 = sigm(gf) * c0 + sigm(gi) * tanha(gg);
      const float h = sigm(go) * tanha(c0);
      int v = (((int)__builtin_rintf(h * 127.f)) & 255) << (8 * (lane & 3));
      v |= dpp_x1(v); v |= dpp_x2(v);
      wA = v;
      if ((lane & 3) == 0) s_h0q[t & 3][jo + (lane >> 2)] = v;
      PUBLISH(wv, t + 1);
      READFLAGS();
    }
  } else if (wv < 4) {
    // ================= L1 half =================
    const int half = wv - 2;
    const int u = (half << 6) | lane;
    const int jo = half << 4, jp = (half ^ 1) << 4;
    int qIo[16], qIp[16], qFo[16], qFp[16];
    int qGo[16], qGp[16], qOo[16], qOp[16];
    float sI, sF, sG, sO;
    {
      const float* p;
      float m, inv;
      p = Whh1 + (size_t)u * Hn;
      m = rowmax128(p); inv = 127.f / m; sI = m * (1.f / 127.f);
      quant16(p, jo, inv, qIo); quant16(p, jp, inv, qIp);
      p = Whh1 + (size_t)(u + 128) * Hn;
      m = rowmax128(p); inv = 127.f / m; sF = m * (1.f / 127.f);
      quant16(p, jo, inv, qFo); quant16(p, jp, inv, qFp);
      p = Whh1 + (size_t)(u + 256) * Hn;
      m = rowmax128(p); inv = 127.f / m; sG = m * (1.f / 127.f);
      quant16(p, jo, inv, qGo); quant16(p, jp, inv, qGp);
      p = Whh1 + (size_t)(u + 384) * Hn;
      m = rowmax128(p); inv = 127.f / m; sO = m * (1.f / 127.f);
      quant16(p, jo, inv, qOo); quant16(p, jp, inv, qOp);
    }
    sI *= (1.f / 127.f); sF *= (1.f / 127.f);
    sG *= (1.f / 127.f); sO *= (1.f / 127.f);
    float c1 = 0.f;
    int wA = 0;
#pragma unroll 1
    for (int t = 0; t < len; ++t) {
      POLL(f03[2 + (half ^ 1)] >= t && imin(f47[0], f47[1]) >= t + 1);
      const int pw = s_h1q[(t + 3) & 3][jp + (lane & 15)];
      const float tvI = s_term[t & 3][0][half][lane];
      const float tvF = s_term[t & 3][1][half][lane];
      const float tvG = s_term[t & 3][2][half][lane];
      const float tvO = s_term[t & 3][3][half][lane];
      int aI = 0, aF = 0, aG = 0, aO = 0;
      {
        int sw[16];
#pragma unroll
        for (int j = 0; j < 16; ++j) sw[j] = __builtin_amdgcn_readlane(wA, 4 * j);
#pragma unroll
        for (int j = 0; j < 16; ++j) {
          aI = sdot4(sw[j], qIo[j], aI); aF = sdot4(sw[j], qFo[j], aF);
          aG = sdot4(sw[j], qGo[j], aG); aO = sdot4(sw[j], qOo[j], aO);
        }
#pragma unroll
        for (int j = 0; j < 16; ++j) sw[j] = __builtin_amdgcn_readlane(pw, j);
#pragma unroll
        for (int j = 0; j < 16; ++j) {
          aI = sdot4(sw[j], qIp[j], aI); aF = sdot4(sw[j], qFp[j], aF);
          aG = sdot4(sw[j], qGp[j], aG); aO = sdot4(sw[j], qOp[j], aO);
        }
      }
      const float gi = tvI + (float)aI * sI;
      const float gf = tvF + (float)aF * sF;
      const float gg = tvG + (float)aG * sG;
      const float go = tvO + (float)aO * sO;
      c1 = sigm(gf) * c1 + sigm(gi) * tanha(gg);
      const float h = sigm(go) * tanha(c1);
      if (t == len - 1) s_h1f[u] = h;
      int v = (((int)__builtin_rintf(h * 127.f)) & 255) << (8 * (lane & 3));
      v |= dpp_x1(v); v |= dpp_x2(v);
      wA = v;
      if ((lane & 3) == 0) s_h1q[t & 3][jo + (lane >> 2)] = v;
      PUBLISH(wv, t + 1);
      READFLAGS();
    }
  } else if (wv < 6) {
    // ================= TERM half: Wih1 . h0(t) for units of this half ====
    const int half = wv - 4;
    const int u = (half << 6) | lane;
    int qI[32], qF[32], qG[32], qO[32];
    float sI, sF, sG, sO;
    quantW128(Wih1 + (size_t)u * Hn, qI, sI);
    quantW128(Wih1 + (size_t)(u + 128) * Hn, qF, sF);
    quantW128(Wih1 + (size_t)(u + 256) * Hn, qG, sG);
    quantW128(Wih1 + (size_t)(u + 384) * Hn, qO, sO);
    sI *= (1.f / 127.f); sF *= (1.f / 127.f);
    sG *= (1.f / 127.f); sO *= (1.f / 127.f);
    const float bI = bih1[u]       + bhh1[u];
    const float bF = bih1[u + 128] + bhh1[u + 128];
    const float bG = bih1[u + 256] + bhh1[u + 256];
    const float bO = bih1[u + 384] + bhh1[u + 384];
#pragma unroll 1
    for (int t = 0; t < len; ++t) {
      POLL(f03[0] >= t + 1 && f03[1] >= t + 1 &&
           imin(f03[2], f03[3]) >= t - 3);
      const int vq = s_h0q[t & 3][lane & 31];  // full 32-word h0(t)
      int aI = 0, aF = 0, aG = 0, aO = 0;
      {
        int sw[32];
#pragma unroll
        for (int j = 0; j < 32; ++j) sw[j] = __builtin_amdgcn_readlane(vq, j);
#pragma unroll
        for (int j = 0; j < 32; ++j) {
          aI = sdot4(sw[j], qI[j], aI); aF = sdot4(sw[j], qF[j], aF);
          aG = sdot4(sw[j], qG[j], aG); aO = sdot4(sw[j], qO[j], aO);
        }
      }
      s_term[t & 3][0][half][lane] = bI + (float)aI * sI;
      s_term[t & 3][1][half][lane] = bF + (float)aF * sF;
      s_term[t & 3][2][half][lane] = bG + (float)aG * sG;
      s_term[t & 3][3][half][lane] = bO + (float)aO * sO;
      PUBLISH(wv, t + 1);
      READFLAGS();
    }
  } else {
    // ================= XP half: x -> f16 -> Wih0 rows of this half =======
    const int half = wv - 6;
    const int u = (half << 6) | lane;  // same rows as L0 half
    int wpA[20], wpB[20], wpC[20], wpD[20];
    {
      const float* p;
      p = Wih0 + (size_t)u * Dn;
#pragma unroll
      for (int w2 = 0; w2 < 20; ++w2) wpA[w2] = pk2i(p[2 * w2], p[2 * w2 + 1]);
      p = Wih0 + (size_t)(u + 128) * Dn;
#pragma unroll
      for (int w2 = 0; w2 < 20; ++w2) wpB[w2] = pk2i(p[2 * w2], p[2 * w2 + 1]);
      p = Wih0 + (size_t)(u + 256) * Dn;
#pragma unroll
      for (int w2 = 0; w2 < 20; ++w2) wpC[w2] = pk2i(p[2 * w2], p[2 * w2 + 1]);
      p = Wih0 + (size_t)(u + 384) * Dn;
#pragma unroll
      for (int w2 = 0; w2 < 20; ++w2) wpD[w2] = pk2i(p[2 * w2], p[2 * w2 + 1]);
    }
    const int nch = (len + 15) >> 4;
#pragma unroll 1
    for (int k = 0; k < nch; ++k) {
      const bool more = (k + 1 < nch);
      if (more) {  // prefetch raw chunk k+1 (own segments)
        const float* xs = x + ((size_t)b * Tn + (size_t)(k + 1) * 16) * Dn;
        if (half == 0) {
#if HAVE_GLDS
          gl_lds16(xs + lane * 4,        &s_xraw[0]);
          gl_lds16(xs + (lane + 64) * 4, &s_xraw[256]);
#else
          *(float4*)&s_xraw[lane * 4] = *(const float4*)(xs + lane * 4);
          *(float4*)&s_xraw[(lane + 64) * 4] = *(const float4*)(xs + (lane + 64) * 4);
#endif
        } else if (lane < 32) {
#if HAVE_GLDS
          gl_lds16(xs + (lane + 128) * 4, &s_xraw[512]);
#else
          *(float4*)&s_xraw[(lane + 128) * 4] = *(const float4*)(xs + (lane + 128) * 4);
#endif
        }
      }
      // project chunk k (partner must have converted chunk k: flag >= 2k)
      POLL(f47[2 + (half ^ 1)] >= 2 * k);
      {
        const int* flat = s_xh2;
        const int st0 = flat[lane], st1 = flat[lane + 64],
                  st2 = flat[lane + 128], st3 = flat[lane + 192],
                  st4 = flat[lane + 256];
#pragma unroll 1
        for (int tl = 0; tl < 16; ++tl) {
          float a0 = 0.f, a1 = 0.f, a2 = 0.f, a3 = 0.f;
#pragma unroll
          for (int w2 = 0; w2 < 20; ++w2) {
            const h2 s = bch(RLST(20 * tl + w2));
            a0 = fdot2f(s, bch(wpA[w2]), a0);
            a1 = fdot2f(s, bch(wpB[w2]), a1);
            a2 = fdot2f(s, bch(wpC[w2]), a2);
            a3 = fdot2f(s, bch(wpD[w2]), a3);
          }
          s_xp[k & 1][tl][half][lane]     = a0;
          s_xp[k & 1][tl][half + 2][lane] = a1;
          s_xp[k & 1][tl][half + 4][lane] = a2;
          s_xp[k & 1][tl][half + 6][lane] = a3;
        }
      }
      PUBLISH(wv, 2 * k + 1);
      if (more) {
        // convert chunk k+1 into shared stash: needs L0 past the buffer we
        // overwrite next AND partner done projecting chunk k from s_xh2
        POLL(imin(f03[0], f03[1]) >= 16 * k &&
             f47[2 + (half ^ 1)] >= 2 * k + 1);
#if HAVE_GLDS
        asm volatile("s_waitcnt vmcnt(0)" ::: "memory");
#endif
        if (half == 0) {
          float4 v = *(const float4*)&s_xraw[4 * lane];
          s_xh2[2 * lane] = pk2i(v.x, v.y);
          s_xh2[2 * lane + 1] = pk2i(v.z, v.w);
          v = *(const float4*)&s_xraw[4 * (lane + 64)];
          s_xh2[2 * (lane + 64)] = pk2i(v.x, v.y);
          s_xh2[2 * (lane + 64) + 1] = pk2i(v.z, v.w);
        } else if (lane < 32) {
          float4 v = *(const float4*)&s_xraw[4 * (lane + 128)];
          s_xh2[2 * (lane + 128)] = pk2i(v.x, v.y);
          s_xh2[2 * (lane + 128) + 1] = pk2i(v.z, v.w);
        }
      }
      PUBLISH(wv, 2 * k + 2);
      READFLAGS();
    }
  }

  __syncthreads();  // all chains done; s_h1f complete

  // ---- LayerNorm over H on wave 0 ----
  if (tid < 64) {
    const float a = s_h1f[tid], d = s_h1f[64 + tid];
    float s = a + d, q = a * a + d * d;
#pragma unroll
    for (int m = 32; m >= 1; m >>= 1) {
      s += __shfl_xor(s, m, 64);
      q += __shfl_xor(q, m, 64);
    }
    const float mu = s * (1.f / 128.f);
    float var = q * (1.f / 128.f) - mu * mu;
    var = fmaxf(var, 0.f);
    const float rstd = rsqrtf(var + 1e-5f);
    s_hn[tid]      = (a - mu) * rstd * gam[tid]      + bet[tid];
    s_hn[64 + tid] = (d - mu) * rstd * gam[64 + tid] + bet[64 + tid];
  }
  __syncthreads();

  // ---- FC head ----
  if (tid < Cn) {
    float acc = fcb[tid];
    const float* wp = fcw + tid * Hn;
#pragma unroll 4
    for (int k = 0; k < Hn; ++k) acc += s_hn[k] * wp[k];
    out[(size_t)b * Cn + tid] = acc;
  }
}

extern "C" void kernel_launch(void* const* d_in, const int* in_sizes, int n_in,
                              void* d_out, int out_size, void* d_ws, size_t ws_size,
                              hipStream_t stream) {
  (void)in_sizes; (void)n_in; (void)d_ws; (void)ws_size; (void)out_size;
  lstm2_fused<<<dim3(Bn), dim3(512), 0, stream>>>(
      (const float*)d_in[0],  (const int*)d_in[1],
      (const float*)d_in[2],  (const float*)d_in[3],
      (const float*)d_in[4],  (const float*)d_in[5],
      (const float*)d_in[6],  (const float*)d_in[7],
      (const float*)d_in[8],  (const float*)d_in[9],
      (const float*)d_in[10], (const float*)d_in[11],
      (const float*)d_in[12], (const float*)d_in[13],
      (float*)d_out);
}

// Round 8
// 2245.939 us; speedup vs baseline: 2.3993x; 1.2276x over previous
//
#include <hip/hip_runtime.h>

#define Bn 256
#define Tn 2048
#define Dn 40
#define Hn 128
#define Cn 35

typedef _Float16 h2 __attribute__((ext_vector_type(2)));

__device__ __forceinline__ int sdot4(int a, int b, int c) {
#if __has_builtin(__builtin_amdgcn_sdot4)
  return __builtin_amdgcn_sdot4(a, b, c, false);
#else
  int r = c;
#pragma unroll
  for (int i = 0; i < 4; ++i)
    r += ((int)(a << (24 - 8 * i)) >> 24) * ((int)(b << (24 - 8 * i)) >> 24);
  return r;
#endif
}

__device__ __forceinline__ float fdot2f(h2 a, h2 b, float c) {
#if __has_builtin(__builtin_amdgcn_fdot2)
  return __builtin_amdgcn_fdot2(a, b, c, false);
#else
  return c + (float)(a[0]) * (float)(b[0]) + (float)(a[1]) * (float)(b[1]);
#endif
}

__device__ __forceinline__ h2 bch(int u) { return __builtin_bit_cast(h2, u); }

__device__ __forceinline__ int pk2i(float a, float b) {  // two f16 in one word
  h2 r; r[0] = (_Float16)a; r[1] = (_Float16)b;
  return __builtin_bit_cast(int, r);
}

__device__ __forceinline__ float rcpf_(float x) {
#if __has_builtin(__builtin_amdgcn_rcpf)
  return __builtin_amdgcn_rcpf(x);
#else
  return 1.f / x;
#endif
}

__device__ __forceinline__ float sigm(float v) {
  v = fmaxf(fminf(v, 60.f), -60.f);
  return rcpf_(1.f + __expf(-v));
}

__device__ __forceinline__ float tanha(float v) {
  v = fmaxf(fminf(v, 15.f), -15.f);
  const float e = __expf(2.f * v);
  return (e - 1.f) * rcpf_(e + 1.f);
}

__device__ __forceinline__ int q8c(float v) {  // round+clamp to [-127,127]
  v = fminf(fmaxf(v, -127.f), 127.f);
  return (int)__builtin_rintf(v);
}

__device__ __forceinline__ int pk4(int a, int b, int c, int d) {
  return (a & 255) | ((b & 255) << 8) | ((c & 255) << 16) | (d << 24);
}

// DPP quad-perm xor-1 / xor-2 (full-rate VALU cross-lane within quads)
__device__ __forceinline__ int dpp_x1(int v) {
  return __builtin_amdgcn_update_dpp(0, v, 0xB1, 0xF, 0xF, true);
}
__device__ __forceinline__ int dpp_x2(int v) {
  return __builtin_amdgcn_update_dpp(0, v, 0x4E, 0xF, 0xF, true);
}

#if __has_builtin(__builtin_amdgcn_global_load_lds)
#define HAVE_GLDS 1
__device__ __forceinline__ void gl_lds16(const float* g, float* l) {
  __builtin_amdgcn_global_load_lds(
      (const __attribute__((address_space(1))) unsigned int*)(const void*)g,
      (__attribute__((address_space(3))) unsigned int*)(void*)l, 16, 0, 0);
}
#endif

// quantize 128 f32 weights -> 32 packed-i8 words + scale (rowmax/127)
__device__ __forceinline__ void quantW128(const float* __restrict__ p,
                                          int* __restrict__ q, float& sc) {
  float m = 1e-30f;
#pragma unroll
  for (int i = 0; i < 32; ++i) {
    const float4 v = reinterpret_cast<const float4*>(p)[i];
    m = fmaxf(m, fmaxf(fmaxf(fabsf(v.x), fabsf(v.y)),
                       fmaxf(fabsf(v.z), fabsf(v.w))));
  }
  const float inv = 127.f / m;
  sc = m * (1.f / 127.f);
#pragma unroll
  for (int i = 0; i < 32; ++i) {
    const float4 v = reinterpret_cast<const float4*>(p)[i];
    q[i] = pk4(q8c(v.x * inv), q8c(v.y * inv), q8c(v.z * inv), q8c(v.w * inv));
  }
}

// readlane word w (0..319) from 5-reg stash (lane L holds flat[L+64k])
#define RLST(w) __builtin_amdgcn_readlane(                                  \
    ((w) < 64 ? st0 : (w) < 128 ? st1 : (w) < 192 ? st2 : (w) < 256 ? st3  \
                                                        : st4), (w) & 63)

#define MEMBAR() asm volatile("" ::: "memory")
// cached poll: touches LDS only when the cached value is insufficient
#define POLL_GE(idx, val, cache)                                             \
  do {                                                                       \
    if ((cache) < (val)) {                                                   \
      do { (cache) = *(volatile int*)&s_flag[idx]; } while ((cache) < (val));\
    }                                                                        \
    MEMBAR();                                                                \
  } while (0)
#define PUBLISH(idx, val)                                                    \
  do {                                                                       \
    MEMBAR();                                                                \
    asm volatile("s_waitcnt lgkmcnt(0)" ::: "memory");                       \
    *(volatile int*)&s_flag[idx] = (val);                                    \
  } while (0)

// r14: r9 chassis (measured best, 2494us) with the per-step sync tax
// amortized. Session-wide evidence: r6 (2-barrier) 2512, r9 (flags) 2494,
// r13 (split flags) 2757 -- all ~2900-3200cy/step at VALUBusy ~31% while
// issue work is only ~1/3 of that. The invariant cost is per-step protocol:
// unconditional READFLAGS refresh (~120cy stall), per-step PUBLISH
// (lgkmcnt(0) drain + MEMBAR pin), and (r13) an in-loop cross-wave hop.
// Changes vs r9 (dots/act/quant bit-identical):
//   1. rings 4 -> 8 deep (h0q, term): backpressure thresholds t-7, cached
//      flag satisfies them ~6 steps -> polls free.
//   2. no unconditional refresh; POLL_GE uses cache, reads LDS on miss only.
//   3. batched publishes: L0 every 2 steps, TERM/L1 every 4 (+ at end).
//      Consumers burst on one flag read; publish cost amortized 2-4x.
//      Ring depth 8 > batch 4 + lag -> no deadlock; final publishes cover
//      the epilogue waits for any len.
// Roles (4 waves, 1/SIMD): w0 L0 (8 Whh0 rows/lane in reg/AGPR, h0 packed
// in-register via DPP), w1 L1 (Whh1, term from ring), w2 TERM (Wih1.h0(t)
// from h0q ring), w3 XP (glds x -> f16 -> Wih0 projection, 16-step chunks).
__global__ __launch_bounds__(256, 1) void lstm2_fused(
    const float* __restrict__ x,
    const int*   __restrict__ length,
    const float* __restrict__ Wih0, const float* __restrict__ Whh0,
    const float* __restrict__ bih0, const float* __restrict__ bhh0,
    const float* __restrict__ Wih1, const float* __restrict__ Whh1,
    const float* __restrict__ bih1, const float* __restrict__ bhh1,
    const float* __restrict__ gam,  const float* __restrict__ bet,
    const float* __restrict__ fcw,  const float* __restrict__ fcb,
    float* __restrict__ out)
{
  __shared__ __align__(16) float s_xraw[160 * 4];  // 2.5 KiB raw x chunk
  __shared__ int   s_xh2[320];                     // 1.25 KiB f16 x chunk
  __shared__ float s_xp[2][16][8][64];             // 64 KiB x-projection
  __shared__ float s_term[8][8][64];               // 16 KiB ih-term ring (8 deep)
  __shared__ int   s_h0q[8][32];                   // 1 KiB packed i8 h0 ring (8 deep)
  __shared__ int   s_flag[4];                      // fL0, fT, fL1, fX
  __shared__ float s_h1f[128];
  __shared__ float s_hn[128];

  const int tid  = threadIdx.x;
  const int lane = tid & 63;
  const int wv   = tid >> 6;          // wave 0..3 (one per SIMD)
  const int b    = blockIdx.x;
  const int len  = length[b];         // 1..2048

  // ---- prologue: chunk-0 raw prefetch (XP wave), zero state ----
  if (wv == 3) {
    const float* xs = x + (size_t)b * Tn * Dn;
#if HAVE_GLDS
    gl_lds16(xs + lane * 4,        &s_xraw[lane * 4]);
    gl_lds16(xs + (lane + 64) * 4, &s_xraw[(lane + 64) * 4]);
    if (lane < 32)
      gl_lds16(xs + (lane + 128) * 4, &s_xraw[(lane + 128) * 4]);
#else
    *(float4*)&s_xraw[lane * 4] = *(const float4*)(xs + lane * 4);
    *(float4*)&s_xraw[(lane + 64) * 4] = *(const float4*)(xs + (lane + 64) * 4);
    if (lane < 32)
      *(float4*)&s_xraw[(lane + 128) * 4] = *(const float4*)(xs + (lane + 128) * 4);
#endif
  }
  ((int*)s_h0q)[tid] = 0;            // 256 ints = whole ring
  if (tid < 4) s_flag[tid] = 0;
  __syncthreads();                   // glds drained; zeros visible
  if (tid < 160) {                   // convert chunk 0 to f16 stash
    const float4 v = *(const float4*)&s_xraw[4 * tid];
    s_xh2[2 * tid]     = pk2i(v.x, v.y);
    s_xh2[2 * tid + 1] = pk2i(v.z, v.w);
  }
  __syncthreads();                   // stash ready for XP's first projection

  // Lane L of a recurrence/term wave owns gate-rows r_k = L + 64k, k=0..7:
  //   unitA=L: k=0(i),2(f),4(g),6(o)   unitB=L+64: k=1,3,5,7
  // h0q ring word j (j<16: units 4j..4j+3; j>=16: +64) <-> quad j.

  if (wv == 0) {
    // ===================== L0 recurrence wave =====================
    int q0[32], q1[32], q2[32], q3[32], q4[32], q5[32], q6[32], q7[32];
    float sc[8], bs[8];
    quantW128(Whh0 + (size_t)(lane)       * Hn, q0, sc[0]);
    quantW128(Whh0 + (size_t)(lane + 64)  * Hn, q1, sc[1]);
    quantW128(Whh0 + (size_t)(lane + 128) * Hn, q2, sc[2]);
    quantW128(Whh0 + (size_t)(lane + 192) * Hn, q3, sc[3]);
    quantW128(Whh0 + (size_t)(lane + 256) * Hn, q4, sc[4]);
    quantW128(Whh0 + (size_t)(lane + 320) * Hn, q5, sc[5]);
    quantW128(Whh0 + (size_t)(lane + 384) * Hn, q6, sc[6]);
    quantW128(Whh0 + (size_t)(lane + 448) * Hn, q7, sc[7]);
#pragma unroll
    for (int k = 0; k < 8; ++k) {
      sc[k] *= (1.f / 127.f);  // fold fixed h-scale
      bs[k] = bih0[lane + 64 * k] + bhh0[lane + 64 * k];
    }
    const int shl = 8 * (lane & 3);
    float cA = 0.f, cB = 0.f;
    int wA = 0, wB = 0;  // packed i8 h0 (own quad's words), 0 at t=0
    int fX = 0, fT = 0;
#pragma unroll 1
    for (int t = 0; t < len; ++t) {
      const int tl = t & 15;
      if (tl == 0) POLL_GE(3, (t >> 4) + 1, fX);   // x-proj chunk ready
      POLL_GE(1, t - 7, fT);                       // export slot free (rare)
      const float* xb = &s_xp[(t >> 4) & 1][tl][0][lane];
      float xv0 = xb[0], xv1 = xb[64], xv2 = xb[128], xv3 = xb[192],
            xv4 = xb[256], xv5 = xb[320], xv6 = xb[384], xv7 = xb[448];
      int a0 = 0, a1 = 0, a2 = 0, a3 = 0, a4 = 0, a5 = 0, a6 = 0, a7 = 0;
#pragma unroll
      for (int j = 0; j < 16; ++j) {
        const int s = __builtin_amdgcn_readlane(wA, 4 * j);
        a0 = sdot4(s, q0[j], a0); a1 = sdot4(s, q1[j], a1);
        a2 = sdot4(s, q2[j], a2); a3 = sdot4(s, q3[j], a3);
        a4 = sdot4(s, q4[j], a4); a5 = sdot4(s, q5[j], a5);
        a6 = sdot4(s, q6[j], a6); a7 = sdot4(s, q7[j], a7);
      }
#pragma unroll
      for (int j = 0; j < 16; ++j) {
        const int s = __builtin_amdgcn_readlane(wB, 4 * j);
        a0 = sdot4(s, q0[16 + j], a0); a1 = sdot4(s, q1[16 + j], a1);
        a2 = sdot4(s, q2[16 + j], a2); a3 = sdot4(s, q3[16 + j], a3);
        a4 = sdot4(s, q4[16 + j], a4); a5 = sdot4(s, q5[16 + j], a5);
        a6 = sdot4(s, q6[16 + j], a6); a7 = sdot4(s, q7[16 + j], a7);
      }
      const float gAi = bs[0] + xv0 + (float)a0 * sc[0];
      const float gBi = bs[1] + xv1 + (float)a1 * sc[1];
      const float gAf = bs[2] + xv2 + (float)a2 * sc[2];
      const float gBf = bs[3] + xv3 + (float)a3 * sc[3];
      const float gAg = bs[4] + xv4 + (float)a4 * sc[4];
      const float gBg = bs[5] + xv5 + (float)a5 * sc[5];
      const float gAo = bs[6] + xv6 + (float)a6 * sc[6];
      const float gBo = bs[7] + xv7 + (float)a7 * sc[7];
      cA = sigm(gAf) * cA + sigm(gAi) * tanha(gAg);
      const float hA = sigm(gAo) * tanha(cA);
      cB = sigm(gBf) * cB + sigm(gBi) * tanha(gBg);
      const float hB = sigm(gBo) * tanha(cB);
      // in-register pack: byte -> quad word via DPP or-reduce
      int vA = (((int)__builtin_rintf(hA * 127.f)) & 255) << shl;
      int vB = (((int)__builtin_rintf(hB * 127.f)) & 255) << shl;
      vA |= dpp_x1(vA); vA |= dpp_x2(vA);
      vB |= dpp_x1(vB); vB |= dpp_x2(vB);
      wA = vA; wB = vB;
      if ((lane & 3) == 0) {  // export for TERM wave
        s_h0q[t & 7][lane >> 2]        = vA;
        s_h0q[t & 7][16 + (lane >> 2)] = vB;
      }
      if ((t & 1) || t == len - 1) PUBLISH(0, t + 1);
    }
  } else if (wv == 1) {
    // ===================== L1 recurrence wave =====================
    int q0[32], q1[32], q2[32], q3[32], q4[32], q5[32], q6[32], q7[32];
    float sc[8];
    quantW128(Whh1 + (size_t)(lane)       * Hn, q0, sc[0]);
    quantW128(Whh1 + (size_t)(lane + 64)  * Hn, q1, sc[1]);
    quantW128(Whh1 + (size_t)(lane + 128) * Hn, q2, sc[2]);
    quantW128(Whh1 + (size_t)(lane + 192) * Hn, q3, sc[3]);
    quantW128(Whh1 + (size_t)(lane + 256) * Hn, q4, sc[4]);
    quantW128(Whh1 + (size_t)(lane + 320) * Hn, q5, sc[5]);
    quantW128(Whh1 + (size_t)(lane + 384) * Hn, q6, sc[6]);
    quantW128(Whh1 + (size_t)(lane + 448) * Hn, q7, sc[7]);
#pragma unroll
    for (int k = 0; k < 8; ++k) sc[k] *= (1.f / 127.f);
    const int shl = 8 * (lane & 3);
    float cA = 0.f, cB = 0.f;
    int wA = 0, wB = 0;
    int fT = 0;
#pragma unroll 1
    for (int t = 0; t < len; ++t) {
      POLL_GE(1, t + 1, fT);                       // term(t) ready
      const float* tb = &s_term[t & 7][0][lane];   // hidden under dot
      float tv0 = tb[0], tv1 = tb[64], tv2 = tb[128], tv3 = tb[192],
            tv4 = tb[256], tv5 = tb[320], tv6 = tb[384], tv7 = tb[448];
      int a0 = 0, a1 = 0, a2 = 0, a3 = 0, a4 = 0, a5 = 0, a6 = 0, a7 = 0;
#pragma unroll
      for (int j = 0; j < 16; ++j) {
        const int s = __builtin_amdgcn_readlane(wA, 4 * j);
        a0 = sdot4(s, q0[j], a0); a1 = sdot4(s, q1[j], a1);
        a2 = sdot4(s, q2[j], a2); a3 = sdot4(s, q3[j], a3);
        a4 = sdot4(s, q4[j], a4); a5 = sdot4(s, q5[j], a5);
        a6 = sdot4(s, q6[j], a6); a7 = sdot4(s, q7[j], a7);
      }
#pragma unroll
      for (int j = 0; j < 16; ++j) {
        const int s = __builtin_amdgcn_readlane(wB, 4 * j);
        a0 = sdot4(s, q0[16 + j], a0); a1 = sdot4(s, q1[16 + j], a1);
        a2 = sdot4(s, q2[16 + j], a2); a3 = sdot4(s, q3[16 + j], a3);
        a4 = sdot4(s, q4[16 + j], a4); a5 = sdot4(s, q5[16 + j], a5);
        a6 = sdot4(s, q6[16 + j], a6); a7 = sdot4(s, q7[16 + j], a7);
      }
      const float gAi = tv0 + (float)a0 * sc[0];
      const float gBi = tv1 + (float)a1 * sc[1];
      const float gAf = tv2 + (float)a2 * sc[2];
      const float gBf = tv3 + (float)a3 * sc[3];
      const float gAg = tv4 + (float)a4 * sc[4];
      const float gBg = tv5 + (float)a5 * sc[5];
      const float gAo = tv6 + (float)a6 * sc[6];
      const float gBo = tv7 + (float)a7 * sc[7];
      cA = sigm(gAf) * cA + sigm(gAi) * tanha(gAg);
      const float hA = sigm(gAo) * tanha(cA);
      cB = sigm(gBf) * cB + sigm(gBi) * tanha(gBg);
      const float hB = sigm(gBo) * tanha(cB);
      if (t == len - 1) { s_h1f[lane] = hA; s_h1f[lane + 64] = hB; }
      int vA = (((int)__builtin_rintf(hA * 127.f)) & 255) << shl;
      int vB = (((int)__builtin_rintf(hB * 127.f)) & 255) << shl;
      vA |= dpp_x1(vA); vA |= dpp_x2(vA);
      vB |= dpp_x1(vB); vB |= dpp_x2(vB);
      wA = vA; wB = vB;
      if (((t & 3) == 3) || t == len - 1) PUBLISH(2, t + 1);  // frees term slots
    }
  } else if (wv == 2) {
    // ===================== TERM wave: Wih1 . h0(t) =====================
    int q0[32], q1[32], q2[32], q3[32], q4[32], q5[32], q6[32], q7[32];
    float sc[8], bs[8];
    quantW128(Wih1 + (size_t)(lane)       * Hn, q0, sc[0]);
    quantW128(Wih1 + (size_t)(lane + 64)  * Hn, q1, sc[1]);
    quantW128(Wih1 + (size_t)(lane + 128) * Hn, q2, sc[2]);
    quantW128(Wih1 + (size_t)(lane + 192) * Hn, q3, sc[3]);
    quantW128(Wih1 + (size_t)(lane + 256) * Hn, q4, sc[4]);
    quantW128(Wih1 + (size_t)(lane + 320) * Hn, q5, sc[5]);
    quantW128(Wih1 + (size_t)(lane + 384) * Hn, q6, sc[6]);
    quantW128(Wih1 + (size_t)(lane + 448) * Hn, q7, sc[7]);
#pragma unroll
    for (int k = 0; k < 8; ++k) {
      sc[k] *= (1.f / 127.f);
      bs[k] = bih1[lane + 64 * k] + bhh1[lane + 64 * k];
    }
    int fL0 = 0, fL1 = 0;
#pragma unroll 1
    for (int t = 0; t < len; ++t) {
      POLL_GE(0, t + 1, fL0);                      // h0(t) exported
      POLL_GE(2, t - 7, fL1);                      // term slot free (rare)
      const int vq = s_h0q[t & 7][lane & 31];
      int a0 = 0, a1 = 0, a2 = 0, a3 = 0, a4 = 0, a5 = 0, a6 = 0, a7 = 0;
#pragma unroll
      for (int j = 0; j < 32; ++j) {
        const int s = __builtin_amdgcn_readlane(vq, j);
        a0 = sdot4(s, q0[j], a0); a1 = sdot4(s, q1[j], a1);
        a2 = sdot4(s, q2[j], a2); a3 = sdot4(s, q3[j], a3);
        a4 = sdot4(s, q4[j], a4); a5 = sdot4(s, q5[j], a5);
        a6 = sdot4(s, q6[j], a6); a7 = sdot4(s, q7[j], a7);
      }
      float* tb = &s_term[t & 7][0][lane];
      tb[0]   = bs[0] + (float)a0 * sc[0];
      tb[64]  = bs[1] + (float)a1 * sc[1];
      tb[128] = bs[2] + (float)a2 * sc[2];
      tb[192] = bs[3] + (float)a3 * sc[3];
      tb[256] = bs[4] + (float)a4 * sc[4];
      tb[320] = bs[5] + (float)a5 * sc[5];
      tb[448] = bs[7] + (float)a7 * sc[7];
      tb[384] = bs[6] + (float)a6 * sc[6];
      if (((t & 3) == 3) || t == len - 1) PUBLISH(1, t + 1);
    }
  } else {
    // ===================== XP wave: x -> f16 -> Wih0 projection =========
    int wp0[20], wp1[20], wp2[20], wp3[20], wp4[20], wp5[20], wp6[20], wp7[20];
    {
      const float* p;
      p = Wih0 + (size_t)(lane)       * Dn;
#pragma unroll
      for (int w = 0; w < 20; ++w) wp0[w] = pk2i(p[2 * w], p[2 * w + 1]);
      p = Wih0 + (size_t)(lane + 64)  * Dn;
#pragma unroll
      for (int w = 0; w < 20; ++w) wp1[w] = pk2i(p[2 * w], p[2 * w + 1]);
      p = Wih0 + (size_t)(lane + 128) * Dn;
#pragma unroll
      for (int w = 0; w < 20; ++w) wp2[w] = pk2i(p[2 * w], p[2 * w + 1]);
      p = Wih0 + (size_t)(lane + 192) * Dn;
#pragma unroll
      for (int w = 0; w < 20; ++w) wp3[w] = pk2i(p[2 * w], p[2 * w + 1]);
      p = Wih0 + (size_t)(lane + 256) * Dn;
#pragma unroll
      for (int w = 0; w < 20; ++w) wp4[w] = pk2i(p[2 * w], p[2 * w + 1]);
      p = Wih0 + (size_t)(lane + 320) * Dn;
#pragma unroll
      for (int w = 0; w < 20; ++w) wp5[w] = pk2i(p[2 * w], p[2 * w + 1]);
      p = Wih0 + (size_t)(lane + 384) * Dn;
#pragma unroll
      for (int w = 0; w < 20; ++w) wp6[w] = pk2i(p[2 * w], p[2 * w + 1]);
      p = Wih0 + (size_t)(lane + 448) * Dn;
#pragma unroll
      for (int w = 0; w < 20; ++w) wp7[w] = pk2i(p[2 * w], p[2 * w + 1]);
    }
    const int nch = (len + 15) >> 4;  // chunks to produce (<=128)
    int fL0 = 0;
#pragma unroll 1
    for (int k = 0; k < nch; ++k) {
      const bool more = (k + 1 < nch);
      if (more) {  // prefetch next raw chunk (hides under projection)
        const float* src = x + ((size_t)b * Tn + (size_t)(k + 1) * 16) * Dn;
#if HAVE_GLDS
        gl_lds16(src + lane * 4,        &s_xraw[lane * 4]);
        gl_lds16(src + (lane + 64) * 4, &s_xraw[(lane + 64) * 4]);
        if (lane < 32)
          gl_lds16(src + (lane + 128) * 4, &s_xraw[(lane + 128) * 4]);
#else
        *(float4*)&s_xraw[lane * 4] = *(const float4*)(src + lane * 4);
        *(float4*)&s_xraw[(lane + 64) * 4] = *(const float4*)(src + (lane + 64) * 4);
        if (lane < 32)
          *(float4*)&s_xraw[(lane + 128) * 4] = *(const float4*)(src + (lane + 128) * 4);
#endif
      }
      // project chunk k from s_xh2 (stash regs consumed before overwrite)
      {
        const int* flat = s_xh2;
        const int st0 = flat[lane], st1 = flat[lane + 64],
                  st2 = flat[lane + 128], st3 = flat[lane + 192],
                  st4 = flat[lane + 256];
#pragma unroll 1
        for (int tl = 0; tl < 16; ++tl) {
          float a0 = 0.f, a1 = 0.f, a2 = 0.f, a3 = 0.f,
                a4 = 0.f, a5 = 0.f, a6 = 0.f, a7 = 0.f;
#pragma unroll
          for (int w = 0; w < 20; ++w) {
            const h2 s = bch(RLST(20 * tl + w));
            a0 = fdot2f(s, bch(wp0[w]), a0); a1 = fdot2f(s, bch(wp1[w]), a1);
            a2 = fdot2f(s, bch(wp2[w]), a2); a3 = fdot2f(s, bch(wp3[w]), a3);
            a4 = fdot2f(s, bch(wp4[w]), a4); a5 = fdot2f(s, bch(wp5[w]), a5);
            a6 = fdot2f(s, bch(wp6[w]), a6); a7 = fdot2f(s, bch(wp7[w]), a7);
          }
          float* xb = &s_xp[k & 1][tl][0][lane];
          xb[0] = a0;   xb[64] = a1;  xb[128] = a2; xb[192] = a3;
          xb[256] = a4; xb[320] = a5; xb[384] = a6; xb[448] = a7;
        }
      }
      PUBLISH(3, k + 1);
      if (more) {
        POLL_GE(0, 16 * k, fL0);  // L0 done with buffer we overwrite next
#if HAVE_GLDS
        asm volatile("s_waitcnt vmcnt(0)" ::: "memory");
#endif
        float4 v = *(const float4*)&s_xraw[4 * lane];
        s_xh2[2 * lane] = pk2i(v.x, v.y); s_xh2[2 * lane + 1] = pk2i(v.z, v.w);
        v = *(const float4*)&s_xraw[4 * (lane + 64)];
        s_xh2[2 * (lane + 64)] = pk2i(v.x, v.y);
        s_xh2[2 * (lane + 64) + 1] = pk2i(v.z, v.w);
        if (lane < 32) {
          v = *(const float4*)&s_xraw[4 * (lane + 128)];
          s_xh2[2 * (lane + 128)] = pk2i(v.x, v.y);
          s_xh2[2 * (lane + 128) + 1] = pk2i(v.z, v.w);
        }
      }
    }
  }

  __syncthreads();  // all chains done; s_h1f complete

  // ---- LayerNorm over H on wave 0 ----
  if (tid < 64) {
    const float a = s_h1f[tid], d = s_h1f[64 + tid];
    float s = a + d, q = a * a + d * d;
#pragma unroll
    for (int m = 32; m >= 1; m >>= 1) {
      s += __shfl_xor(s, m, 64);
      q += __shfl_xor(q, m, 64);
    }
    const float mu = s * (1.f / 128.f);
    float var = q * (1.f / 128.f) - mu * mu;
    var = fmaxf(var, 0.f);
    const float rstd = rsqrtf(var + 1e-5f);
    s_hn[tid]      = (a - mu) * rstd * gam[tid]      + bet[tid];
    s_hn[64 + tid] = (d - mu) * rstd * gam[64 + tid] + bet[64 + tid];
  }
  __syncthreads();

  // ---- FC head ----
  if (tid < Cn) {
    float acc = fcb[tid];
    const float* wp = fcw + tid * Hn;
#pragma unroll 4
    for (int k = 0; k < Hn; ++k) acc += s_hn[k] * wp[k];
    out[(size_t)b * Cn + tid] = acc;
  }
}

extern "C" void kernel_launch(void* const* d_in, const int* in_sizes, int n_in,
                              void* d_out, int out_size, void* d_ws, size_t ws_size,
                              hipStream_t stream) {
  (void)in_sizes; (void)n_in; (void)d_ws; (void)ws_size; (void)out_size;
  lstm2_fused<<<dim3(Bn), dim3(256), 0, stream>>>(
      (const float*)d_in[0],  (const int*)d_in[1],
      (const float*)d_in[2],  (const float*)d_in[3],
      (const float*)d_in[4],  (const float*)d_in[5],
      (const float*)d_in[6],  (const float*)d_in[7],
      (const float*)d_in[8],  (const float*)d_in[9],
      (const float*)d_in[10], (const float*)d_in[11],
      (const float*)d_in[12], (const float*)d_in[13],
      (float*)d_out);
}